// Round 5
// baseline (22879.361 us; speedup 1.0000x reference)
//
#include <hip/hip_runtime.h>

// ---------------- problem constants ----------------
#define T_STEPS 256
#define BATCH   64
#define DIN     512
#define HID     1024
#define NCOLS   4096   // 4*HID
#define NBLK    64     // persistent blocks (communication scales with this)
#define TPB     256    // 4 waves

typedef __attribute__((ext_vector_type(8))) short short8;
typedef __attribute__((ext_vector_type(4))) float float4v;
typedef unsigned long long u64;

union Frag { u64 u[2]; short8 s; };

__device__ __forceinline__ short f2bf(float x) {
    unsigned u = __float_as_uint(x);
    u += 0x7FFFu + ((u >> 16) & 1u);   // RNE
    return (short)(u >> 16);
}
__device__ __forceinline__ float sigmoidf_(float x) { return 1.0f / (1.0f + __expf(-x)); }
__device__ __forceinline__ float tanhf_(float x)    { return 1.0f - 2.0f / (__expf(2.0f * x) + 1.0f); }

// ---------------- prologue kernels ----------------
__global__ void cvt_bf16_kernel(const float* __restrict__ src, short* __restrict__ dst, int n) {
    int i = blockIdx.x * blockDim.x + threadIdx.x;
    int stride = gridDim.x * blockDim.x;
    for (; i < n; i += stride) dst[i] = f2bf(src[i]);
}

// src: R x C fp32 row-major -> dst: C x R bf16 row-major
__global__ void transpose_bf16_kernel(const float* __restrict__ src, short* __restrict__ dst,
                                      int R, int C) {
    __shared__ float tile[32][33];
    int tx = threadIdx.x, ty = threadIdx.y;
    int r0 = blockIdx.y * 32, c0 = blockIdx.x * 32;
#pragma unroll
    for (int i = 0; i < 32; i += 8)
        tile[ty + i][tx] = src[(size_t)(r0 + ty + i) * C + (c0 + tx)];
    __syncthreads();
#pragma unroll
    for (int i = 0; i < 32; i += 8)
        dst[(size_t)(c0 + ty + i) * R + (r0 + tx)] = f2bf(tile[tx][ty + i]);
}

// ---------------- fused persistent LSTM ----------------
// 64 blocks. Block wg owns H-cols [wg*16, wg*16+16) => 64 s-cols
// l = gate*16 + jj  (gate 0..3 = f,i,o,g ; jj 0..15 local H-col).
// Wave w computes batch rows [16w,16w+16) for ALL 64 s-cols (4 MFMAs/chunk).
// Cross-block data (h, y0, flags) via relaxed agent-scope atomics (cache
// bypass, no fences => weights/x stay L2-resident). h double-buffered by
// t parity. Barrier: 64 padded flags, each wave polls one flag per lane.
__global__ __launch_bounds__(TPB, 1) void lstm_persist(
    const int* __restrict__ length,
    const float* __restrict__ b0,  const float* __restrict__ g_ih0, const float* __restrict__ bt_ih0,
    const float* __restrict__ g_hh0, const float* __restrict__ bt_hh0,
    const float* __restrict__ g_c0,  const float* __restrict__ bt_c0,
    const float* __restrict__ b1,  const float* __restrict__ g_ih1, const float* __restrict__ bt_ih1,
    const float* __restrict__ g_hh1, const float* __restrict__ bt_hh1,
    const float* __restrict__ g_c1,  const float* __restrict__ bt_c1,
    const short* __restrict__ xb, short* __restrict__ y0b,
    const short* __restrict__ wih0T, const short* __restrict__ whh0T,
    const short* __restrict__ wih1T, const short* __restrict__ whh1T,
    short* __restrict__ h0A, short* __restrict__ h0B,
    short* __restrict__ h1A, short* __restrict__ h1B,
    unsigned* __restrict__ flags,
    float* __restrict__ out)
{
    const int wg   = blockIdx.x;
    const int tid  = threadIdx.x;
    const int wave = tid >> 6;
    const int lane = tid & 63;
    const int nidx = lane & 15;
    const int quad = lane >> 4;

    __shared__ float st_s[4][16][66];      // s tile: [wave][row][l] (+pad)
    __shared__ float red_h[4][4][16][2];   // [wave][g][jj][s1,s2]
    __shared__ float red_i[4][4][16][2];
    __shared__ float red_c[16][17][2];     // [j][m0][s,q]
    __shared__ unsigned short hpub[64][16];// packed h(t) tile for coalesced publish

    const int m_row = wave * 16 + nidx;    // A-fragment batch row

    // gate-phase mapping: thread = (j, m0), rows m0+16w
    const int j   = tid & 15;
    const int m0  = tid >> 4;
    const int j_gl = wg * 16 + j;
    int len4[4];
#pragma unroll
    for (int r_ = 0; r_ < 4; ++r_) len4[r_] = length[m0 + 16 * r_];

    // publish-phase mapping: thread = (row, seg)
    const int p_row = tid >> 2;
    const int p_seg = tid & 3;

    const float inv64 = 1.0f / 64.0f;

#pragma unroll
    for (int layer = 0; layer < 2; ++layer) {
        const int K  = layer ? HID : DIN;
        const int KI = K >> 5;
        const short* xin  = layer ? y0b   : xb;
        const short* wTih = layer ? wih1T : wih0T;
        const short* wThh = layer ? whh1T : whh0T;
        short* hA = layer ? h1A : h0A;
        short* hB = layer ? h1B : h0B;

        // per-lane BN params for s-phase cols (g*1024 + wg*16 + nidx)
        float gih_g[4], btih_g[4], ghh_g[4], bthh_g[4], bb_g[4];
#pragma unroll
        for (int g = 0; g < 4; ++g) {
            int col = g * HID + wg * 16 + nidx;
            gih_g[g]  = (layer ? g_ih1  : g_ih0 )[col];
            btih_g[g] = (layer ? bt_ih1 : bt_ih0)[col];
            ghh_g[g]  = (layer ? g_hh1  : g_hh0)[col];
            bthh_g[g] = (layer ? bt_hh1 : bt_hh0)[col];
            bb_g[g]   = (layer ? b1     : b0   )[col];
        }
        const float gcv  = (layer ? g_c1  : g_c0 )[j_gl];
        const float btcv = (layer ? bt_c1 : bt_c0)[j_gl];

        // B pointers (cached loads; stay L2-resident — no fences anywhere)
        const short8* Bih[4];
        const short8* Bhh[4];
#pragma unroll
        for (int g = 0; g < 4; ++g) {
            int col = g * HID + wg * 16 + nidx;
            Bih[g] = (const short8*)wTih + (((size_t)col * K)   >> 3) + quad;
            Bhh[g] = (const short8*)wThh + (((size_t)col * HID) >> 3) + quad;
        }

        float h_st[4] = {0.f, 0.f, 0.f, 0.f};
        float c_st[4] = {0.f, 0.f, 0.f, 0.f};

#pragma unroll 1
        for (int t = 0; t < T_STEPS; ++t) {
            const short* hb_r = (t & 1) ? hB : hA;   // holds h(t-1)
            short*       hb_w = (t & 1) ? hA : hB;   // becomes h(t)

            // ---- ih GEMM (independent of h(t-1); overlaps the wait) ----
            const short8* Axp = (const short8*)xin + (((size_t)(t * BATCH + m_row) * K) >> 3) + quad;
            float4v ai[4];
#pragma unroll
            for (int g = 0; g < 4; ++g) ai[g] = (float4v){0.f, 0.f, 0.f, 0.f};
#pragma unroll
            for (int kk = 0; kk < 32; ++kk) {
                if (kk < KI) {
                    short8 a = Axp[kk * 4];
#pragma unroll
                    for (int g = 0; g < 4; ++g)
                        ai[g] = __builtin_amdgcn_mfma_f32_16x16x32_bf16(a, Bih[g][kk * 4], ai[g], 0, 0, 0);
                }
            }

            // ---- grid wait: each wave polls 64 flags (1/lane) ----
            const unsigned need = (unsigned)(layer * T_STEPS + t);
            if (need > 0u) {
                for (;;) {
                    unsigned f = __hip_atomic_load(&flags[lane * 16], __ATOMIC_RELAXED,
                                                   __HIP_MEMORY_SCOPE_AGENT);
                    if (__ballot(f >= need) == ~0ull) break;
                    __builtin_amdgcn_s_sleep(1);
                }
            }

            // ---- hh A-fragments: h(t-1) via cache-bypass loads ----
            u64 A2[64];
            const u64* hp = (const u64*)hb_r + (size_t)m_row * (HID / 4) + quad * 2;
#pragma unroll
            for (int kk = 0; kk < 32; ++kk) {
                A2[2 * kk]     = __hip_atomic_load(hp + kk * 8,     __ATOMIC_RELAXED, __HIP_MEMORY_SCOPE_AGENT);
                A2[2 * kk + 1] = __hip_atomic_load(hp + kk * 8 + 1, __ATOMIC_RELAXED, __HIP_MEMORY_SCOPE_AGENT);
            }
            float4v ah[4];
#pragma unroll
            for (int g = 0; g < 4; ++g) ah[g] = (float4v){0.f, 0.f, 0.f, 0.f};
#pragma unroll
            for (int kk = 0; kk < 32; ++kk) {
                Frag fa;
                fa.u[0] = A2[2 * kk]; fa.u[1] = A2[2 * kk + 1];
#pragma unroll
                for (int g = 0; g < 4; ++g)
                    ah[g] = __builtin_amdgcn_mfma_f32_16x16x32_bf16(fa.s, Bhh[g][kk * 4], ah[g], 0, 0, 0);
            }

            // ---- per-column batch stats (sum, sumsq over 16 rows/wave) ----
#pragma unroll
            for (int g = 0; g < 4; ++g) {
                float s1h = ah[g][0] + ah[g][1] + ah[g][2] + ah[g][3];
                float s2h = ah[g][0]*ah[g][0] + ah[g][1]*ah[g][1] + ah[g][2]*ah[g][2] + ah[g][3]*ah[g][3];
                float s1i = ai[g][0] + ai[g][1] + ai[g][2] + ai[g][3];
                float s2i = ai[g][0]*ai[g][0] + ai[g][1]*ai[g][1] + ai[g][2]*ai[g][2] + ai[g][3]*ai[g][3];
                s1h += __shfl_xor(s1h, 16); s1h += __shfl_xor(s1h, 32);
                s2h += __shfl_xor(s2h, 16); s2h += __shfl_xor(s2h, 32);
                s1i += __shfl_xor(s1i, 16); s1i += __shfl_xor(s1i, 32);
                s2i += __shfl_xor(s2i, 16); s2i += __shfl_xor(s2i, 32);
                if (quad == 0) {
                    red_h[wave][g][nidx][0] = s1h; red_h[wave][g][nidx][1] = s2h;
                    red_i[wave][g][nidx][0] = s1i; red_i[wave][g][nidx][1] = s2i;
                }
            }
            __syncthreads();
            // combine across waves + write normalized s tile
#pragma unroll
            for (int g = 0; g < 4; ++g) {
                float th = 0.f, qh = 0.f, ti = 0.f, qi = 0.f;
#pragma unroll
                for (int w = 0; w < 4; ++w) {
                    th += red_h[w][g][nidx][0]; qh += red_h[w][g][nidx][1];
                    ti += red_i[w][g][nidx][0]; qi += red_i[w][g][nidx][1];
                }
                float muh = th * inv64, vah = qh * inv64 - muh * muh;
                float mui = ti * inv64, vai = qi * inv64 - mui * mui;
                float rsh = rsqrtf(vah + 1e-5f), rsi = rsqrtf(vai + 1e-5f);
#pragma unroll
                for (int r = 0; r < 4; ++r) {
                    float sv = ghh_g[g] * (ah[g][r] - muh) * rsh + bthh_g[g]
                             + gih_g[g] * (ai[g][r] - mui) * rsi + btih_g[g] + bb_g[g];
                    st_s[wave][quad * 4 + r][g * 16 + nidx] = sv;
                }
            }
            __syncthreads();

            // ---- gates + c update (thread = (j, m0), 4 rows) ----
            float c1v[4], ovv[4];
            float ps = 0.f, pq = 0.f;
#pragma unroll
            for (int r_ = 0; r_ < 4; ++r_) {
                float fv = st_s[r_][m0][0 * 16 + j];
                float iv = st_s[r_][m0][1 * 16 + j];
                ovv[r_]  = st_s[r_][m0][2 * 16 + j];
                float gv = st_s[r_][m0][3 * 16 + j];
                c1v[r_] = sigmoidf_(fv) * c_st[r_] + sigmoidf_(iv) * tanhf_(gv);
                ps += c1v[r_]; pq += c1v[r_] * c1v[r_];
            }
            red_c[j][m0][0] = ps; red_c[j][m0][1] = pq;
            __syncthreads();
            float tc = 0.f, qc = 0.f;
#pragma unroll
            for (int i = 0; i < 16; ++i) { tc += red_c[j][i][0]; qc += red_c[j][i][1]; }
            float muc = tc * inv64, vac = qc * inv64 - muc * muc;
            float rsc = rsqrtf(vac + 1e-5f);
#pragma unroll
            for (int r_ = 0; r_ < 4; ++r_) {
                float bnc = gcv * (c1v[r_] - muc) * rsc + btcv;
                float h1 = sigmoidf_(ovv[r_]) * tanhf_(bnc);
                bool mk = (t < len4[r_]);
                h_st[r_] = mk ? h1 : h_st[r_];
                c_st[r_] = mk ? c1v[r_] : c_st[r_];
                hpub[m0 + 16 * r_][j] = (unsigned short)f2bf(h_st[r_]);
                if (layer == 1)
                    out[(size_t)(t * BATCH + m0 + 16 * r_) * HID + j_gl] = h_st[r_];
            }
            __syncthreads();

            // ---- coalesced publish: 8B bypass stores of h(t) (+ y0) ----
            {
                u64 pk = *(const u64*)&hpub[p_row][p_seg * 4];
                size_t sidx = (size_t)p_row * HID + wg * 16 + p_seg * 4;   // bf16 idx
                __hip_atomic_store((u64*)hb_w + (sidx >> 2), pk,
                                   __ATOMIC_RELAXED, __HIP_MEMORY_SCOPE_AGENT);
                if (layer == 0) {
                    size_t yidx = (size_t)(t * BATCH + p_row) * HID + wg * 16 + p_seg * 4;
                    __hip_atomic_store((u64*)y0b + (yidx >> 2), pk,
                                       __ATOMIC_RELAXED, __HIP_MEMORY_SCOPE_AGENT);
                }
            }

            // ---- arrive: drain stores, then flag ----
            __builtin_amdgcn_s_waitcnt(0);
            __syncthreads();
            if (tid == 0)
                __hip_atomic_store(&flags[wg * 16], need + 1u, __ATOMIC_RELAXED,
                                   __HIP_MEMORY_SCOPE_AGENT);
        }

        // final h_n / c_n for this layer, from registers
        {
            const size_t ybase = (size_t)T_STEPS * BATCH * HID;
#pragma unroll
            for (int r_ = 0; r_ < 4; ++r_) {
                int m = m0 + 16 * r_;
                out[ybase + (size_t)layer * BATCH * HID + (size_t)m * HID + j_gl] = h_st[r_];
                out[ybase + (size_t)(2 + layer) * BATCH * HID + (size_t)m * HID + j_gl] = c_st[r_];
            }
        }
    }
}

// ---------------- launch ----------------
extern "C" void kernel_launch(void* const* d_in, const int* in_sizes, int n_in,
                              void* d_out, int out_size, void* d_ws, size_t ws_size,
                              hipStream_t stream)
{
    const float* x      = (const float*)d_in[0];
    const int*   length = (const int*)  d_in[1];
    const float* w_ih0  = (const float*)d_in[2];
    const float* w_hh0  = (const float*)d_in[3];
    const float* b0     = (const float*)d_in[4];
    const float* g_ih0  = (const float*)d_in[5];
    const float* bt_ih0 = (const float*)d_in[6];
    const float* g_hh0  = (const float*)d_in[7];
    const float* bt_hh0 = (const float*)d_in[8];
    const float* g_c0   = (const float*)d_in[9];
    const float* bt_c0  = (const float*)d_in[10];
    const float* w_ih1  = (const float*)d_in[11];
    const float* w_hh1  = (const float*)d_in[12];
    const float* b1     = (const float*)d_in[13];
    const float* g_ih1  = (const float*)d_in[14];
    const float* bt_ih1 = (const float*)d_in[15];
    const float* g_hh1  = (const float*)d_in[16];
    const float* bt_hh1 = (const float*)d_in[17];
    const float* g_c1   = (const float*)d_in[18];
    const float* bt_c1  = (const float*)d_in[19];

    char* ws = (char*)d_ws;
    // workspace layout (16B-aligned throughout)
    unsigned* flags = (unsigned*)(ws + 0);          // 64 flags, 64B stride = 4096 B
    short* h0A   = (short*)(ws + 4096);             // 131072 B
    short* h0B   = (short*)(ws + 135168);           // 131072 B
    short* h1A   = (short*)(ws + 266240);           // 131072 B
    short* h1B   = (short*)(ws + 397312);           // 131072 B
    // ---- end of zeroed region: 528384 ----
    short* xb    = (short*)(ws + 528384);           // 16777216 B
    short* y0b   = (short*)(ws + 17305600);         // 33554432 B
    short* wih0T = (short*)(ws + 50860032);         // 4194304 B
    short* whh0T = (short*)(ws + 55054336);         // 8388608 B
    short* wih1T = (short*)(ws + 63442944);         // 8388608 B
    short* whh1T = (short*)(ws + 71831552);         // 8388608 B
    // total footprint: 80,220,160 bytes

    // zero flags + h double-buffers (harness re-poisons ws each timed launch)
    (void)hipMemsetAsync(ws, 0, 528384, stream);

    cvt_bf16_kernel<<<2048, 256, 0, stream>>>(x, xb, T_STEPS * BATCH * DIN);

    dim3 tb(32, 8);
    transpose_bf16_kernel<<<dim3(NCOLS / 32, DIN / 32), tb, 0, stream>>>(w_ih0, wih0T, DIN, NCOLS);
    transpose_bf16_kernel<<<dim3(NCOLS / 32, HID / 32), tb, 0, stream>>>(w_hh0, whh0T, HID, NCOLS);
    transpose_bf16_kernel<<<dim3(NCOLS / 32, HID / 32), tb, 0, stream>>>(w_ih1, wih1T, HID, NCOLS);
    transpose_bf16_kernel<<<dim3(NCOLS / 32, HID / 32), tb, 0, stream>>>(w_hh1, whh1T, HID, NCOLS);

    lstm_persist<<<NBLK, TPB, 0, stream>>>(
        length,
        b0, g_ih0, bt_ih0, g_hh0, bt_hh0, g_c0, bt_c0,
        b1, g_ih1, bt_ih1, g_hh1, bt_hh1, g_c1, bt_c1,
        xb, y0b, wih0T, whh0T, wih1T, whh1T,
        h0A, h0B, h1A, h1B,
        flags,
        (float*)d_out);
}